// Round 5
// baseline (762.461 us; speedup 1.0000x reference)
//
#include <hip/hip_runtime.h>
#include <hip/hip_bf16.h>

#define NN 20000
#define NE 320000
#define DD 256

typedef __attribute__((ext_vector_type(8))) short bf16x8;   // 8 bf16 = 4 VGPR (MFMA A/B frag)
typedef __attribute__((ext_vector_type(4))) float f32x4;    // MFMA C/D frag
typedef __attribute__((ext_vector_type(4))) int   int4v;    // 16B chunk
typedef __attribute__((ext_vector_type(4))) float float4v;

typedef __attribute__((address_space(1))) unsigned int gas_uint;
typedef __attribute__((address_space(3))) unsigned int las_uint;
static __device__ __forceinline__ void gload16(const void* g, void* l) {
    __builtin_amdgcn_global_load_lds((gas_uint*)g, (las_uint*)l, 16, 0, 0);
}

__device__ __forceinline__ unsigned short f2bf(float f) {
    union { float f; unsigned u; } v; v.f = f;
    unsigned r = v.u + 0x7fffu + ((v.u >> 16) & 1u);   // RNE
    return (unsigned short)(r >> 16);
}
__device__ __forceinline__ float bf2f(unsigned short h) {
    union { unsigned u; float f; } v; v.u = ((unsigned)h) << 16;
    return v.f;
}
__device__ __forceinline__ float fast_sigmoid(float x) {
    return 1.f / (1.f + __expf(-x));                   // inf-safe: 1/(1+inf)=0
}
__device__ __forceinline__ float fast_tanh(float x) {
    x = fminf(fmaxf(x, -30.f), 30.f);                  // clamp: avoid inf/inf NaN
    float e = __expf(-2.f * x);
    return (1.f - e) / (1.f + e);
}

// ---------------- prologue kernels ----------------

// Wt[l][n][k] = W[l][k][n], cast to bf16 (B^T layout)
__global__ void tw_kernel(const float* __restrict__ W, unsigned short* __restrict__ Wt) {
    int id = blockIdx.x * 256 + threadIdx.x;          // 5*256*256
    int l = id >> 16, rem = id & 65535;
    int k = rem >> 8, n = rem & 255;
    Wt[l * 65536 + n * 256 + k] = f2bf(W[id]);
}

__global__ void cast_kernel(const float* __restrict__ in, unsigned short* __restrict__ out, int n) {
    int i = (blockIdx.x * blockDim.x + threadIdx.x) * 4;
    if (i >= n) return;
    float4v v = *reinterpret_cast<const float4v*>(in + i);
    uint2 o;
    o.x = (unsigned)f2bf(v.x) | ((unsigned)f2bf(v.y) << 16);
    o.y = (unsigned)f2bf(v.z) | ((unsigned)f2bf(v.w) << 16);
    *reinterpret_cast<uint2*>(out + i) = o;
}

// Combined permuted GRU weight: Wc[n'][k], n' = (d>>4)*64 + g*16 + (d&15), k in [0,512)
__global__ void wc_kernel(const float* __restrict__ wih, const float* __restrict__ whh,
                          unsigned short* __restrict__ Wc) {
    int id = blockIdx.x * 256 + threadIdx.x;          // 1024*512 elements
    int np = id >> 9, k = id & 511;
    int g = (np >> 4) & 3;
    int d = ((np >> 6) << 4) | (np & 15);
    float v;
    if (g < 2)       v = (k < 256) ? wih[(g * 256 + d) * 256 + k] : whh[(g * 256 + d) * 256 + (k - 256)];
    else if (g == 2) v = (k < 256) ? wih[(512 + d) * 256 + k] : 0.f;
    else             v = (k >= 256) ? whh[(512 + d) * 256 + (k - 256)] : 0.f;
    Wc[(size_t)np * 512 + k] = f2bf(v);
}

// ---------------- CSR build (once per launch) ----------------

__global__ void hist_kernel(const int* __restrict__ dst, int* __restrict__ deg) {
    int e = blockIdx.x * 256 + threadIdx.x;
    if (e < NE) atomicAdd(&deg[dst[e]], 1);
}

__global__ __launch_bounds__(1024) void scan_kernel(const int* __restrict__ deg, int* __restrict__ base) {
    __shared__ int part[1024];
    const int t = threadIdx.x;
    const int CH = 20;
    int start = t * CH;
    int s = 0;
    for (int i = 0; i < CH; ++i) { int idx = start + i; if (idx < NN) s += deg[idx]; }
    part[t] = s; __syncthreads();
    for (int off = 1; off < 1024; off <<= 1) {
        int v = (t >= off) ? part[t - off] : 0;
        __syncthreads();
        part[t] += v;
        __syncthreads();
    }
    int run = (t == 0) ? 0 : part[t - 1];
    for (int i = 0; i < CH; ++i) {
        int idx = start + i;
        if (idx < NN) { base[idx] = run; run += deg[idx]; }
    }
    if (t == 1023) base[NN] = run;
}

__global__ void fill_kernel(const int* __restrict__ src, const int* __restrict__ dst,
                            const float* __restrict__ attr, const int* __restrict__ base,
                            int* __restrict__ cursor, int* __restrict__ ssrc,
                            float* __restrict__ sattr) {
    int e = blockIdx.x * 256 + threadIdx.x;
    if (e >= NE) return;
    int d = dst[e];
    int pos = base[d] + atomicAdd(&cursor[d], 1);
    ssrc[pos] = src[e];
    sattr[pos] = attr[e];
}

// ---------------- GEMM: m_bf = h_bf @ W (Wt is [N][K] bf16) ----------------
// BM=128, BN=64, BK=64; SINGLE-buffered 24KB LDS -> 5+ blocks/CU (TLP hides the drain).
__global__ __launch_bounds__(256, 5) void gemm_m_kernel(const unsigned short* __restrict__ A,
                                                        const unsigned short* __restrict__ Bt,
                                                        unsigned short* __restrict__ C) {
    __shared__ __align__(16) unsigned short As[128 * 64];
    __shared__ __align__(16) unsigned short Bs[64 * 64];
    const int t = threadIdx.x;
    const int lane = t & 63;
    const int w = t >> 6;
    const int wr = w >> 1, wc = w & 1;
    const int m0 = blockIdx.y * 128;
    const int n0 = blockIdx.x * 64;

    f32x4 acc[4][2];
    const f32x4 z4 = {0.f, 0.f, 0.f, 0.f};
    for (int i = 0; i < 4; ++i) for (int j = 0; j < 2; ++j) acc[i][j] = z4;

    for (int kt = 0; kt < 4; ++kt) {
        const int k0 = kt * 64;
#pragma unroll
        for (int rnd = 0; rnd < 4; ++rnd) {            // A: 1024 chunks
            int cb = rnd * 256 + (w << 6);
            int c = cb + lane;
            int row = c >> 3, sl = c & 7;
            int gsl = sl ^ (row & 7);
            gload16(A + (size_t)(m0 + row) * 256 + k0 + gsl * 8, &As[cb * 8]);
        }
#pragma unroll
        for (int rnd = 0; rnd < 2; ++rnd) {            // B: 512 chunks
            int cb = rnd * 256 + (w << 6);
            int c = cb + lane;
            int row = c >> 3, sl = c & 7;
            int gsl = sl ^ (row & 7);
            gload16(Bt + (size_t)(n0 + row) * 256 + k0 + gsl * 8, &Bs[cb * 8]);
        }
        __syncthreads();
#pragma unroll
        for (int ks = 0; ks < 2; ++ks) {
            const int slot = ks * 4 + (lane >> 4);
            bf16x8 a[4], b[2];
#pragma unroll
            for (int mi = 0; mi < 4; ++mi) {
                int row = wr * 64 + mi * 16 + (lane & 15);
                a[mi] = *reinterpret_cast<const bf16x8*>(&As[row * 64 + ((slot ^ (row & 7)) << 3)]);
            }
#pragma unroll
            for (int ni = 0; ni < 2; ++ni) {
                int row = wc * 32 + ni * 16 + (lane & 15);
                b[ni] = *reinterpret_cast<const bf16x8*>(&Bs[row * 64 + ((slot ^ (row & 7)) << 3)]);
            }
            __builtin_amdgcn_s_setprio(1);
#pragma unroll
            for (int mi = 0; mi < 4; ++mi)
#pragma unroll
                for (int ni = 0; ni < 2; ++ni)
                    acc[mi][ni] = __builtin_amdgcn_mfma_f32_16x16x32_bf16(a[mi], b[ni], acc[mi][ni], 0, 0, 0);
            __builtin_amdgcn_s_setprio(0);
        }
        __syncthreads();
    }
#pragma unroll
    for (int mi = 0; mi < 4; ++mi)
#pragma unroll
        for (int ni = 0; ni < 2; ++ni)
#pragma unroll
            for (int r = 0; r < 4; ++r) {
                int grow = m0 + wr * 64 + mi * 16 + (lane >> 4) * 4 + r;
                int gcol = n0 + wc * 32 + ni * 16 + (lane & 15);
                if (grow < NN) C[(size_t)grow * 256 + gcol] = f2bf(acc[mi][ni][r]);
            }
}

// ---------------- aggregation (R2, kept) ----------------
__global__ __launch_bounds__(256) void gather_agg_kernel(const unsigned short* __restrict__ Mbf,
                                                         const int* __restrict__ base,
                                                         const int* __restrict__ ssrc,
                                                         const float* __restrict__ sattr,
                                                         unsigned short* __restrict__ AggBf) {
    int node = blockIdx.x * 4 + (threadIdx.x >> 6);
    if (node >= NN) return;
    int lane = threadIdx.x & 63;
    int half = lane >> 5;
    int dl = lane & 31;
    int b0 = base[node], b1 = base[node + 1];
    float ac[8] = {0.f, 0.f, 0.f, 0.f, 0.f, 0.f, 0.f, 0.f};
    for (int p = b0 + half; p < b1; p += 2) {
        int s = ssrc[p];
        float a = sattr[p];
        int4v v = *reinterpret_cast<const int4v*>(Mbf + (size_t)s * 256 + dl * 8);
        ac[0] += a * bf2f((unsigned short)(v.x & 0xffff));
        ac[1] += a * bf2f((unsigned short)((unsigned)v.x >> 16));
        ac[2] += a * bf2f((unsigned short)(v.y & 0xffff));
        ac[3] += a * bf2f((unsigned short)((unsigned)v.y >> 16));
        ac[4] += a * bf2f((unsigned short)(v.z & 0xffff));
        ac[5] += a * bf2f((unsigned short)((unsigned)v.z >> 16));
        ac[6] += a * bf2f((unsigned short)(v.w & 0xffff));
        ac[7] += a * bf2f((unsigned short)((unsigned)v.w >> 16));
    }
#pragma unroll
    for (int j = 0; j < 8; ++j) ac[j] += __shfl_xor(ac[j], 32);
    if (half == 0) {
        int4v o;
        o.x = (int)((unsigned)f2bf(ac[0]) | ((unsigned)f2bf(ac[1]) << 16));
        o.y = (int)((unsigned)f2bf(ac[2]) | ((unsigned)f2bf(ac[3]) << 16));
        o.z = (int)((unsigned)f2bf(ac[4]) | ((unsigned)f2bf(ac[5]) << 16));
        o.w = (int)((unsigned)f2bf(ac[6]) | ((unsigned)f2bf(ac[7]) << 16));
        *reinterpret_cast<int4v*>(AggBf + (size_t)node * 256 + dl * 8) = o;
    }
}

// ---------------- GRU as clean GEMM: C = [Abf|Hbf] (M x 512) @ Wc^T (1024 x 512) ----------------
// BM=128, BN=128, BK=64, 4 waves 2x2; SINGLE-buffered 32KB LDS -> 5 blocks/CU (20 waves),
// m97 2-barrier loop, XCD-chunked swizzle, fully in-register gate epilogue.
__global__ __launch_bounds__(256, 5) void gru_kernel(const unsigned short* __restrict__ Abf,
                                                     const unsigned short* __restrict__ Hbf,
                                                     const unsigned short* __restrict__ Wc,
                                                     const float* __restrict__ b_ih,
                                                     const float* __restrict__ b_hh,
                                                     const float* __restrict__ h_in,
                                                     float* __restrict__ h_out,
                                                     unsigned short* __restrict__ Hbf_out) {
    __shared__ __align__(16) unsigned short As[128 * 64];
    __shared__ __align__(16) unsigned short Bs[128 * 64];
    const int t = threadIdx.x;
    const int lane = t & 63;
    const int w = t >> 6;
    const int wr = w >> 1, wc = w & 1;
    int b = blockIdx.x;
    int ww = (b & 7) * 157 + (b >> 3);                 // XCD-chunked (1256 = 8*157, exact)
    const int mt = ww >> 3, nt = ww & 7;
    const int m0 = mt * 128;
    const int n0 = nt * 128;

    f32x4 acc[4][4];
    const f32x4 z4 = {0.f, 0.f, 0.f, 0.f};
#pragma unroll
    for (int i = 0; i < 4; ++i)
#pragma unroll
        for (int j = 0; j < 4; ++j) acc[i][j] = z4;

    for (int kt = 0; kt < 8; ++kt) {
        const unsigned short* aptr = (kt < 4) ? Abf : Hbf;
        const int ka = (kt & 3) * 64;
        const int kb = kt * 64;
#pragma unroll
        for (int i = 0; i < 4; ++i) {
            int cb = i * 256 + (w << 6);
            int c = cb + lane;
            int row = c >> 3, sl = c & 7;
            int gsl = sl ^ (row & 7);                  // pre-swizzled global source, linear LDS dest
            gload16(aptr + (size_t)(m0 + row) * 256 + ka + gsl * 8, &As[cb * 8]);
            gload16(Wc + (size_t)(n0 + row) * 512 + kb + gsl * 8, &Bs[cb * 8]);
        }
        __syncthreads();                               // vmcnt(0) drain + barrier (hidden by TLP)
#pragma unroll
        for (int ks = 0; ks < 2; ++ks) {
            const int slot = ks * 4 + (lane >> 4);
            bf16x8 a[4], bfr[4];
#pragma unroll
            for (int mi = 0; mi < 4; ++mi) {
                int row = wr * 64 + mi * 16 + (lane & 15);
                a[mi] = *reinterpret_cast<const bf16x8*>(&As[row * 64 + ((slot ^ (row & 7)) << 3)]);
            }
#pragma unroll
            for (int g = 0; g < 4; ++g) {
                int row = wc * 64 + g * 16 + (lane & 15);
                bfr[g] = *reinterpret_cast<const bf16x8*>(&Bs[row * 64 + ((slot ^ (row & 7)) << 3)]);
            }
            __builtin_amdgcn_s_setprio(1);
#pragma unroll
            for (int mi = 0; mi < 4; ++mi)
#pragma unroll
                for (int g = 0; g < 4; ++g)
                    acc[mi][g] = __builtin_amdgcn_mfma_f32_16x16x32_bf16(a[mi], bfr[g], acc[mi][g], 0, 0, 0);
            __builtin_amdgcn_s_setprio(0);
        }
        __syncthreads();
    }

    // ---- fused GRU gate epilogue (all 4 gates in-register per thread) ----
    const int c = lane & 15;
    const int d = (nt * 2 + wc) * 16 + c;              // output channel 0..255
    const float bir = b_ih[d],       bhr = b_hh[d];
    const float biz = b_ih[256 + d], bhz = b_hh[256 + d];
    const float bin_ = b_ih[512 + d], bhn = b_hh[512 + d];
#pragma unroll
    for (int mi = 0; mi < 4; ++mi)
#pragma unroll
        for (int r = 0; r < 4; ++r) {
            int grow = m0 + wr * 64 + mi * 16 + (lane >> 4) * 4 + r;
            if (grow >= NN) continue;
            float rr = fast_sigmoid(acc[mi][0][r] + bir + bhr);
            float zz = fast_sigmoid(acc[mi][1][r] + biz + bhz);
            float nn = fast_tanh(acc[mi][2][r] + bin_ + rr * (acc[mi][3][r] + bhn));
            float hp = h_in[(size_t)grow * 256 + d];
            float hv = (1.f - zz) * nn + zz * hp;
            h_out[(size_t)grow * 256 + d] = hv;
            Hbf_out[(size_t)grow * 256 + d] = f2bf(hv);
        }
}

// ---------------- launch ----------------

extern "C" void kernel_launch(void* const* d_in, const int* in_sizes, int n_in,
                              void* d_out, int out_size, void* d_ws, size_t ws_size,
                              hipStream_t stream) {
    const float* x     = (const float*)d_in[0];
    const int*   eidx  = (const int*)d_in[1];
    const float* eattr = (const float*)d_in[2];
    const float* W     = (const float*)d_in[3];
    const float* wih   = (const float*)d_in[4];
    const float* whh   = (const float*)d_in[5];
    const float* bih   = (const float*)d_in[6];
    const float* bhh   = (const float*)d_in[7];
    float* out = (float*)d_out;
    const int* esrc = eidx;
    const int* edst = eidx + NE;

    char* p = (char*)d_ws;
    auto alloc = [&](size_t bytes) -> char* {
        char* r = p; p += (bytes + 255) & ~(size_t)255; return r;
    };
    unsigned short* hbfA  = (unsigned short*)alloc((size_t)NN * DD * 2);
    unsigned short* hbfB  = (unsigned short*)alloc((size_t)NN * DD * 2);
    unsigned short* mbf   = (unsigned short*)alloc((size_t)NN * DD * 2);
    unsigned short* aggbf = (unsigned short*)alloc((size_t)NN * DD * 2);
    unsigned short* Wt    = (unsigned short*)alloc((size_t)5 * DD * DD * 2);
    unsigned short* Wc    = (unsigned short*)alloc((size_t)1024 * 512 * 2);
    int*   deg    = (int*)alloc((size_t)NN * 4);
    int*   basep  = (int*)alloc((size_t)(NN + 1) * 4);
    int*   cursor = (int*)alloc((size_t)NN * 4);
    int*   ssrc   = (int*)alloc((size_t)NE * 4);
    float* sattr  = (float*)alloc((size_t)NE * 4);
    alloc(262144);  // guard slack: padded tile rows (20000..20223) read in-workspace garbage

    hipMemsetAsync(deg, 0, (size_t)NN * 4, stream);
    hipMemsetAsync(cursor, 0, (size_t)NN * 4, stream);

    tw_kernel<<<1280, 256, 0, stream>>>(W, Wt);
    wc_kernel<<<2048, 256, 0, stream>>>(wih, whh, Wc);
    cast_kernel<<<5000, 256, 0, stream>>>(x, hbfA, NN * DD);
    hist_kernel<<<1250, 256, 0, stream>>>(edst, deg);
    scan_kernel<<<1, 1024, 0, stream>>>(deg, basep);
    fill_kernel<<<1250, 256, 0, stream>>>(esrc, edst, eattr, basep, cursor, ssrc, sattr);

    unsigned short* hb_cur = hbfA;
    unsigned short* hb_nxt = hbfB;
    const float* h_in = x;
    for (int l = 0; l < 5; ++l) {
        gemm_m_kernel<<<dim3(4, 157), 256, 0, stream>>>(hb_cur, Wt + (size_t)l * DD * DD, mbf);
        gather_agg_kernel<<<5000, 256, 0, stream>>>(mbf, basep, ssrc, sattr, aggbf);
        gru_kernel<<<1256, 256, 0, stream>>>(aggbf, hb_cur, Wc, bih, bhh, h_in, out, hb_nxt);
        h_in = out;
        unsigned short* tmp = hb_cur; hb_cur = hb_nxt; hb_nxt = tmp;
    }
}

// Round 6
// 511.068 us; speedup vs baseline: 1.4919x; 1.4919x over previous
//
#include <hip/hip_runtime.h>
#include <hip/hip_bf16.h>

#define NN 20000
#define NE 320000
#define DD 256

typedef __attribute__((ext_vector_type(8))) short bf16x8;   // 8 bf16 = 4 VGPR (MFMA A/B frag)
typedef __attribute__((ext_vector_type(4))) float f32x4;    // MFMA C/D frag
typedef __attribute__((ext_vector_type(4))) int   int4v;    // 16B chunk
typedef __attribute__((ext_vector_type(4))) float float4v;

typedef __attribute__((address_space(1))) unsigned int gas_uint;
typedef __attribute__((address_space(3))) unsigned int las_uint;
static __device__ __forceinline__ void gload16(const void* g, void* l) {
    __builtin_amdgcn_global_load_lds((gas_uint*)g, (las_uint*)l, 16, 0, 0);
}

// raw barrier (no implicit vmcnt(0) drain) + counted vmem waits; both are IR memory fences
#define SBAR()   asm volatile("s_barrier" ::: "memory")
#define WAITV(N) asm volatile("s_waitcnt vmcnt(" #N ")" ::: "memory")

__device__ __forceinline__ unsigned short f2bf(float f) {
    union { float f; unsigned u; } v; v.f = f;
    unsigned r = v.u + 0x7fffu + ((v.u >> 16) & 1u);   // RNE
    return (unsigned short)(r >> 16);
}
__device__ __forceinline__ float bf2f(unsigned short h) {
    union { unsigned u; float f; } v; v.u = ((unsigned)h) << 16;
    return v.f;
}
__device__ __forceinline__ float fast_sigmoid(float x) {
    return 1.f / (1.f + __expf(-x));                   // inf-safe: 1/(1+inf)=0
}
__device__ __forceinline__ float fast_tanh(float x) {
    x = fminf(fmaxf(x, -30.f), 30.f);                  // clamp: avoid inf/inf NaN
    float e = __expf(-2.f * x);
    return (1.f - e) / (1.f + e);
}

// ---------------- prologue kernels ----------------

// Wt[l][n][k] = W[l][k][n], cast to bf16 (B^T layout)
__global__ void tw_kernel(const float* __restrict__ W, unsigned short* __restrict__ Wt) {
    int id = blockIdx.x * 256 + threadIdx.x;          // 5*256*256
    int l = id >> 16, rem = id & 65535;
    int k = rem >> 8, n = rem & 255;
    Wt[l * 65536 + n * 256 + k] = f2bf(W[id]);
}

__global__ void cast_kernel(const float* __restrict__ in, unsigned short* __restrict__ out, int n) {
    int i = (blockIdx.x * blockDim.x + threadIdx.x) * 4;
    if (i >= n) return;
    float4v v = *reinterpret_cast<const float4v*>(in + i);
    uint2 o;
    o.x = (unsigned)f2bf(v.x) | ((unsigned)f2bf(v.y) << 16);
    o.y = (unsigned)f2bf(v.z) | ((unsigned)f2bf(v.w) << 16);
    *reinterpret_cast<uint2*>(out + i) = o;
}

// Combined permuted GRU weight: Wc[n'][k], n' = (d>>4)*64 + g*16 + (d&15), k in [0,512)
__global__ void wc_kernel(const float* __restrict__ wih, const float* __restrict__ whh,
                          unsigned short* __restrict__ Wc) {
    int id = blockIdx.x * 256 + threadIdx.x;          // 1024*512 elements
    int np = id >> 9, k = id & 511;
    int g = (np >> 4) & 3;
    int d = ((np >> 6) << 4) | (np & 15);
    float v;
    if (g < 2)       v = (k < 256) ? wih[(g * 256 + d) * 256 + k] : whh[(g * 256 + d) * 256 + (k - 256)];
    else if (g == 2) v = (k < 256) ? wih[(512 + d) * 256 + k] : 0.f;
    else             v = (k >= 256) ? whh[(512 + d) * 256 + (k - 256)] : 0.f;
    Wc[(size_t)np * 512 + k] = f2bf(v);
}

// ---------------- CSR build (once per launch) ----------------

__global__ void hist_kernel(const int* __restrict__ dst, int* __restrict__ deg) {
    int e = blockIdx.x * 256 + threadIdx.x;
    if (e < NE) atomicAdd(&deg[dst[e]], 1);
}

__global__ __launch_bounds__(1024) void scan_kernel(const int* __restrict__ deg, int* __restrict__ base) {
    __shared__ int part[1024];
    const int t = threadIdx.x;
    const int CH = 20;
    int start = t * CH;
    int s = 0;
    for (int i = 0; i < CH; ++i) { int idx = start + i; if (idx < NN) s += deg[idx]; }
    part[t] = s; __syncthreads();
    for (int off = 1; off < 1024; off <<= 1) {
        int v = (t >= off) ? part[t - off] : 0;
        __syncthreads();
        part[t] += v;
        __syncthreads();
    }
    int run = (t == 0) ? 0 : part[t - 1];
    for (int i = 0; i < CH; ++i) {
        int idx = start + i;
        if (idx < NN) { base[idx] = run; run += deg[idx]; }
    }
    if (t == 1023) base[NN] = run;
}

__global__ void fill_kernel(const int* __restrict__ src, const int* __restrict__ dst,
                            const float* __restrict__ attr, const int* __restrict__ base,
                            int* __restrict__ cursor, int* __restrict__ ssrc,
                            float* __restrict__ sattr) {
    int e = blockIdx.x * 256 + threadIdx.x;
    if (e >= NE) return;
    int d = dst[e];
    int pos = base[d] + atomicAdd(&cursor[d], 1);
    ssrc[pos] = src[e];
    sattr[pos] = attr[e];
}

// ---------------- GEMM: m_bf = h_bf @ W (Wt is [N][K] bf16) ----------------
// BM=128, BN=64, BK=64; dbuf LDS (48KB), counted-vmcnt pipeline. (R4, kept)
__global__ __launch_bounds__(256) void gemm_m_kernel(const unsigned short* __restrict__ A,
                                                     const unsigned short* __restrict__ Bt,
                                                     unsigned short* __restrict__ C) {
    __shared__ __align__(16) unsigned short As[2][128 * 64];
    __shared__ __align__(16) unsigned short Bs[2][64 * 64];
    const int t = threadIdx.x;
    const int lane = t & 63;
    const int w = t >> 6;
    const int wr = w >> 1, wc = w & 1;
    const int m0 = blockIdx.y * 128;
    const int n0 = blockIdx.x * 64;

    f32x4 acc[4][2];
    const f32x4 z4 = {0.f, 0.f, 0.f, 0.f};
    for (int i = 0; i < 4; ++i) for (int j = 0; j < 2; ++j) acc[i][j] = z4;

    auto stage = [&](int buf, int kt) {
        const int k0 = kt * 64;
#pragma unroll
        for (int rnd = 0; rnd < 4; ++rnd) {            // A: 1024 chunks
            int cb = rnd * 256 + (w << 6);
            int c = cb + lane;
            int row = c >> 3, sl = c & 7;
            int gsl = sl ^ (row & 7);
            gload16(A + (size_t)(m0 + row) * 256 + k0 + gsl * 8, &As[buf][cb * 8]);
        }
#pragma unroll
        for (int rnd = 0; rnd < 2; ++rnd) {            // B: 512 chunks
            int cb = rnd * 256 + (w << 6);
            int c = cb + lane;
            int row = c >> 3, sl = c & 7;
            int gsl = sl ^ (row & 7);
            gload16(Bt + (size_t)(n0 + row) * 256 + k0 + gsl * 8, &Bs[buf][cb * 8]);
        }
    };

    stage(0, 0);
    stage(1, 1);
    WAITV(6);                                          // tile-0's 6 loads done; tile-1 in flight
    SBAR();
    int cur = 0;
    for (int kt = 0; kt < 4; ++kt) {
#pragma unroll
        for (int ks = 0; ks < 2; ++ks) {
            const int slot = ks * 4 + (lane >> 4);
            bf16x8 a[4], b[2];
#pragma unroll
            for (int mi = 0; mi < 4; ++mi) {
                int row = wr * 64 + mi * 16 + (lane & 15);
                a[mi] = *reinterpret_cast<const bf16x8*>(&As[cur][row * 64 + ((slot ^ (row & 7)) << 3)]);
            }
#pragma unroll
            for (int ni = 0; ni < 2; ++ni) {
                int row = wc * 32 + ni * 16 + (lane & 15);
                b[ni] = *reinterpret_cast<const bf16x8*>(&Bs[cur][row * 64 + ((slot ^ (row & 7)) << 3)]);
            }
#pragma unroll
            for (int mi = 0; mi < 4; ++mi)
#pragma unroll
                for (int ni = 0; ni < 2; ++ni)
                    acc[mi][ni] = __builtin_amdgcn_mfma_f32_16x16x32_bf16(a[mi], b[ni], acc[mi][ni], 0, 0, 0);
        }
        if (kt == 3) break;
        SBAR();                                        // all waves done reading buf[cur]
        if (kt < 2) { stage(cur, kt + 2); WAITV(6); }  // kt+1's 6 done, kt+2's stay in flight
        else        { WAITV(0); }
        SBAR();                                        // buf[cur^1] published
        cur ^= 1;
    }
#pragma unroll
    for (int mi = 0; mi < 4; ++mi)
#pragma unroll
        for (int ni = 0; ni < 2; ++ni)
#pragma unroll
            for (int r = 0; r < 4; ++r) {
                int grow = m0 + wr * 64 + mi * 16 + (lane >> 4) * 4 + r;
                int gcol = n0 + wc * 32 + ni * 16 + (lane & 15);
                if (grow < NN) C[(size_t)grow * 256 + gcol] = f2bf(acc[mi][ni][r]);
            }
}

// ---------------- aggregation (R2, kept) ----------------
__global__ __launch_bounds__(256) void gather_agg_kernel(const unsigned short* __restrict__ Mbf,
                                                         const int* __restrict__ base,
                                                         const int* __restrict__ ssrc,
                                                         const float* __restrict__ sattr,
                                                         unsigned short* __restrict__ AggBf) {
    int node = blockIdx.x * 4 + (threadIdx.x >> 6);
    if (node >= NN) return;
    int lane = threadIdx.x & 63;
    int half = lane >> 5;
    int dl = lane & 31;
    int b0 = base[node], b1 = base[node + 1];
    float ac[8] = {0.f, 0.f, 0.f, 0.f, 0.f, 0.f, 0.f, 0.f};
    for (int p = b0 + half; p < b1; p += 2) {
        int s = ssrc[p];
        float a = sattr[p];
        int4v v = *reinterpret_cast<const int4v*>(Mbf + (size_t)s * 256 + dl * 8);
        ac[0] += a * bf2f((unsigned short)(v.x & 0xffff));
        ac[1] += a * bf2f((unsigned short)((unsigned)v.x >> 16));
        ac[2] += a * bf2f((unsigned short)(v.y & 0xffff));
        ac[3] += a * bf2f((unsigned short)((unsigned)v.y >> 16));
        ac[4] += a * bf2f((unsigned short)(v.z & 0xffff));
        ac[5] += a * bf2f((unsigned short)((unsigned)v.z >> 16));
        ac[6] += a * bf2f((unsigned short)(v.w & 0xffff));
        ac[7] += a * bf2f((unsigned short)((unsigned)v.w >> 16));
    }
#pragma unroll
    for (int j = 0; j < 8; ++j) ac[j] += __shfl_xor(ac[j], 32);
    if (half == 0) {
        int4v o;
        o.x = (int)((unsigned)f2bf(ac[0]) | ((unsigned)f2bf(ac[1]) << 16));
        o.y = (int)((unsigned)f2bf(ac[2]) | ((unsigned)f2bf(ac[3]) << 16));
        o.z = (int)((unsigned)f2bf(ac[4]) | ((unsigned)f2bf(ac[5]) << 16));
        o.w = (int)((unsigned)f2bf(ac[6]) | ((unsigned)f2bf(ac[7]) << 16));
        *reinterpret_cast<int4v*>(AggBf + (size_t)node * 256 + dl * 8) = o;
    }
}

// ---------------- GRU as clean GEMM: C = [Abf|Hbf] (M x 512) @ Wc^T (1024 x 512) ----------------
// BM=128, BN=128, BK=64, 4 waves 2x2; SINGLE-buffered 32KB LDS, natural VGPR (~88):
// 4 waves/SIMD by VGPR, 4+ blocks/CU -> cross-block TLP hides the per-block barrier drain.
// m97 2-barrier loop, XCD-chunked swizzle, fully in-register gate epilogue.
__global__ __launch_bounds__(256) void gru_kernel(const unsigned short* __restrict__ Abf,
                                                  const unsigned short* __restrict__ Hbf,
                                                  const unsigned short* __restrict__ Wc,
                                                  const float* __restrict__ b_ih,
                                                  const float* __restrict__ b_hh,
                                                  const float* __restrict__ h_in,
                                                  float* __restrict__ h_out,
                                                  unsigned short* __restrict__ Hbf_out) {
    __shared__ __align__(16) unsigned short As[128 * 64];
    __shared__ __align__(16) unsigned short Bs[128 * 64];
    const int t = threadIdx.x;
    const int lane = t & 63;
    const int w = t >> 6;
    const int wr = w >> 1, wc = w & 1;
    int b = blockIdx.x;
    int ww = (b & 7) * 157 + (b >> 3);                 // XCD-chunked (1256 = 8*157, exact)
    const int mt = ww >> 3, nt = ww & 7;
    const int m0 = mt * 128;
    const int n0 = nt * 128;

    f32x4 acc[4][4];
    const f32x4 z4 = {0.f, 0.f, 0.f, 0.f};
#pragma unroll
    for (int i = 0; i < 4; ++i)
#pragma unroll
        for (int j = 0; j < 4; ++j) acc[i][j] = z4;

    for (int kt = 0; kt < 8; ++kt) {
        const unsigned short* aptr = (kt < 4) ? Abf : Hbf;
        const int ka = (kt & 3) * 64;
        const int kb = kt * 64;
#pragma unroll
        for (int i = 0; i < 4; ++i) {
            int cb = i * 256 + (w << 6);
            int c = cb + lane;
            int row = c >> 3, sl = c & 7;
            int gsl = sl ^ (row & 7);                  // pre-swizzled global source, linear LDS dest
            gload16(aptr + (size_t)(m0 + row) * 256 + ka + gsl * 8, &As[cb * 8]);
            gload16(Wc + (size_t)(n0 + row) * 512 + kb + gsl * 8, &Bs[cb * 8]);
        }
        __syncthreads();                               // vmcnt(0) drain + barrier (hidden by TLP)
#pragma unroll
        for (int ks = 0; ks < 2; ++ks) {
            const int slot = ks * 4 + (lane >> 4);
            bf16x8 a[4], bfr[4];
#pragma unroll
            for (int mi = 0; mi < 4; ++mi) {
                int row = wr * 64 + mi * 16 + (lane & 15);
                a[mi] = *reinterpret_cast<const bf16x8*>(&As[row * 64 + ((slot ^ (row & 7)) << 3)]);
            }
#pragma unroll
            for (int g = 0; g < 4; ++g) {
                int row = wc * 64 + g * 16 + (lane & 15);
                bfr[g] = *reinterpret_cast<const bf16x8*>(&Bs[row * 64 + ((slot ^ (row & 7)) << 3)]);
            }
#pragma unroll
            for (int mi = 0; mi < 4; ++mi)
#pragma unroll
                for (int g = 0; g < 4; ++g)
                    acc[mi][g] = __builtin_amdgcn_mfma_f32_16x16x32_bf16(a[mi], bfr[g], acc[mi][g], 0, 0, 0);
        }
        __syncthreads();
    }

    // ---- fused GRU gate epilogue (all 4 gates in-register per thread) ----
    const int c = lane & 15;
    const int d = (nt * 2 + wc) * 16 + c;              // output channel 0..255
    const float bir = b_ih[d],       bhr = b_hh[d];
    const float biz = b_ih[256 + d], bhz = b_hh[256 + d];
    const float bin_ = b_ih[512 + d], bhn = b_hh[512 + d];
#pragma unroll
    for (int mi = 0; mi < 4; ++mi)
#pragma unroll
        for (int r = 0; r < 4; ++r) {
            int grow = m0 + wr * 64 + mi * 16 + (lane >> 4) * 4 + r;
            if (grow >= NN) continue;
            float rr = fast_sigmoid(acc[mi][0][r] + bir + bhr);
            float zz = fast_sigmoid(acc[mi][1][r] + biz + bhz);
            float nn = fast_tanh(acc[mi][2][r] + bin_ + rr * (acc[mi][3][r] + bhn));
            float hp = h_in[(size_t)grow * 256 + d];
            float hv = (1.f - zz) * nn + zz * hp;
            h_out[(size_t)grow * 256 + d] = hv;
            Hbf_out[(size_t)grow * 256 + d] = f2bf(hv);
        }
}

// ---------------- launch ----------------

extern "C" void kernel_launch(void* const* d_in, const int* in_sizes, int n_in,
                              void* d_out, int out_size, void* d_ws, size_t ws_size,
                              hipStream_t stream) {
    const float* x     = (const float*)d_in[0];
    const int*   eidx  = (const int*)d_in[1];
    const float* eattr = (const float*)d_in[2];
    const float* W     = (const float*)d_in[3];
    const float* wih   = (const float*)d_in[4];
    const float* whh   = (const float*)d_in[5];
    const float* bih   = (const float*)d_in[6];
    const float* bhh   = (const float*)d_in[7];
    float* out = (float*)d_out;
    const int* esrc = eidx;
    const int* edst = eidx + NE;

    char* p = (char*)d_ws;
    auto alloc = [&](size_t bytes) -> char* {
        char* r = p; p += (bytes + 255) & ~(size_t)255; return r;
    };
    unsigned short* hbfA  = (unsigned short*)alloc((size_t)NN * DD * 2);
    unsigned short* hbfB  = (unsigned short*)alloc((size_t)NN * DD * 2);
    unsigned short* mbf   = (unsigned short*)alloc((size_t)NN * DD * 2);
    unsigned short* aggbf = (unsigned short*)alloc((size_t)NN * DD * 2);
    unsigned short* Wt    = (unsigned short*)alloc((size_t)5 * DD * DD * 2);
    unsigned short* Wc    = (unsigned short*)alloc((size_t)1024 * 512 * 2);
    int*   deg    = (int*)alloc((size_t)NN * 4);
    int*   basep  = (int*)alloc((size_t)(NN + 1) * 4);
    int*   cursor = (int*)alloc((size_t)NN * 4);
    int*   ssrc   = (int*)alloc((size_t)NE * 4);
    float* sattr  = (float*)alloc((size_t)NE * 4);
    alloc(262144);  // guard slack: padded tile rows (20000..20223) read in-workspace garbage

    hipMemsetAsync(deg, 0, (size_t)NN * 4, stream);
    hipMemsetAsync(cursor, 0, (size_t)NN * 4, stream);

    tw_kernel<<<1280, 256, 0, stream>>>(W, Wt);
    wc_kernel<<<2048, 256, 0, stream>>>(wih, whh, Wc);
    cast_kernel<<<5000, 256, 0, stream>>>(x, hbfA, NN * DD);
    hist_kernel<<<1250, 256, 0, stream>>>(edst, deg);
    scan_kernel<<<1, 1024, 0, stream>>>(deg, basep);
    fill_kernel<<<1250, 256, 0, stream>>>(esrc, edst, eattr, basep, cursor, ssrc, sattr);

    unsigned short* hb_cur = hbfA;
    unsigned short* hb_nxt = hbfB;
    const float* h_in = x;
    for (int l = 0; l < 5; ++l) {
        gemm_m_kernel<<<dim3(4, 157), 256, 0, stream>>>(hb_cur, Wt + (size_t)l * DD * DD, mbf);
        gather_agg_kernel<<<5000, 256, 0, stream>>>(mbf, basep, ssrc, sattr, aggbf);
        gru_kernel<<<1256, 256, 0, stream>>>(aggbf, hb_cur, Wc, bih, bhh, h_in, out, hb_nxt);
        h_in = out;
        unsigned short* tmp = hb_cur; hb_cur = hb_nxt; hb_nxt = tmp;
    }
}

// Round 7
// 381.713 us; speedup vs baseline: 1.9975x; 1.3389x over previous
//
#include <hip/hip_runtime.h>
#include <hip/hip_bf16.h>

#define NN 20000
#define NE 320000
#define DD 256

typedef __attribute__((ext_vector_type(8))) short bf16x8;   // 8 bf16 = 4 VGPR (MFMA A/B frag)
typedef __attribute__((ext_vector_type(4))) float f32x4;    // MFMA C/D frag
typedef __attribute__((ext_vector_type(4))) int   int4v;    // 16B chunk
typedef __attribute__((ext_vector_type(4))) float float4v;

typedef __attribute__((address_space(1))) unsigned int gas_uint;
typedef __attribute__((address_space(3))) unsigned int las_uint;
static __device__ __forceinline__ void gload16(const void* g, void* l) {
    __builtin_amdgcn_global_load_lds((gas_uint*)g, (las_uint*)l, 16, 0, 0);
}

__device__ __forceinline__ unsigned short f2bf(float f) {
    union { float f; unsigned u; } v; v.f = f;
    unsigned r = v.u + 0x7fffu + ((v.u >> 16) & 1u);   // RNE
    return (unsigned short)(r >> 16);
}
__device__ __forceinline__ float bf2f(unsigned short h) {
    union { unsigned u; float f; } v; v.u = ((unsigned)h) << 16;
    return v.f;
}
__device__ __forceinline__ float fast_sigmoid(float x) {
    return 1.f / (1.f + __expf(-x));                   // inf-safe: 1/(1+inf)=0
}
__device__ __forceinline__ float fast_tanh(float x) {
    x = fminf(fmaxf(x, -30.f), 30.f);                  // clamp: avoid inf/inf NaN
    float e = __expf(-2.f * x);
    return (1.f - e) / (1.f + e);
}

// ---------------- prologue kernels ----------------

__global__ void cast_kernel(const float* __restrict__ in, unsigned short* __restrict__ out, int n) {
    int i = (blockIdx.x * blockDim.x + threadIdx.x) * 4;
    if (i >= n) return;
    float4v v = *reinterpret_cast<const float4v*>(in + i);
    uint2 o;
    o.x = (unsigned)f2bf(v.x) | ((unsigned)f2bf(v.y) << 16);
    o.y = (unsigned)f2bf(v.z) | ((unsigned)f2bf(v.w) << 16);
    *reinterpret_cast<uint2*>(out + i) = o;
}

// P_all = W_all @ Wih^T : A [1280][256] bf16 (natural W layout), Bt [768][256] bf16,
// C [1280][768] bf16. BM=128,BN=64,BK=64; single-buffer m97 loop (one-off tiny GEMM).
__global__ __launch_bounds__(256) void pgemm_kernel(const unsigned short* __restrict__ A,
                                                    const unsigned short* __restrict__ Bt,
                                                    unsigned short* __restrict__ C) {
    __shared__ __align__(16) unsigned short As[128 * 64];
    __shared__ __align__(16) unsigned short Bs[64 * 64];
    const int t = threadIdx.x;
    const int lane = t & 63;
    const int w = t >> 6;
    const int wr = w >> 1, wc = w & 1;
    const int m0 = blockIdx.y * 128;
    const int n0 = blockIdx.x * 64;

    f32x4 acc[4][2];
    const f32x4 z4 = {0.f, 0.f, 0.f, 0.f};
    for (int i = 0; i < 4; ++i) for (int j = 0; j < 2; ++j) acc[i][j] = z4;

    for (int kt = 0; kt < 4; ++kt) {
        const int k0 = kt * 64;
#pragma unroll
        for (int rnd = 0; rnd < 4; ++rnd) {            // A: 1024 chunks
            int cb = rnd * 256 + (w << 6);
            int c = cb + lane;
            int row = c >> 3, sl = c & 7;
            int gsl = sl ^ (row & 7);
            gload16(A + (size_t)(m0 + row) * 256 + k0 + gsl * 8, &As[cb * 8]);
        }
#pragma unroll
        for (int rnd = 0; rnd < 2; ++rnd) {            // B: 512 chunks
            int cb = rnd * 256 + (w << 6);
            int c = cb + lane;
            int row = c >> 3, sl = c & 7;
            int gsl = sl ^ (row & 7);
            gload16(Bt + (size_t)(n0 + row) * 256 + k0 + gsl * 8, &Bs[cb * 8]);
        }
        __syncthreads();
#pragma unroll
        for (int ks = 0; ks < 2; ++ks) {
            const int slot = ks * 4 + (lane >> 4);
            bf16x8 a[4], b[2];
#pragma unroll
            for (int mi = 0; mi < 4; ++mi) {
                int row = wr * 64 + mi * 16 + (lane & 15);
                a[mi] = *reinterpret_cast<const bf16x8*>(&As[row * 64 + ((slot ^ (row & 7)) << 3)]);
            }
#pragma unroll
            for (int ni = 0; ni < 2; ++ni) {
                int row = wc * 32 + ni * 16 + (lane & 15);
                b[ni] = *reinterpret_cast<const bf16x8*>(&Bs[row * 64 + ((slot ^ (row & 7)) << 3)]);
            }
#pragma unroll
            for (int mi = 0; mi < 4; ++mi)
#pragma unroll
                for (int ni = 0; ni < 2; ++ni)
                    acc[mi][ni] = __builtin_amdgcn_mfma_f32_16x16x32_bf16(a[mi], b[ni], acc[mi][ni], 0, 0, 0);
        }
        __syncthreads();
    }
#pragma unroll
    for (int mi = 0; mi < 4; ++mi)
#pragma unroll
        for (int ni = 0; ni < 2; ++ni)
#pragma unroll
            for (int r = 0; r < 4; ++r) {
                int grow = m0 + wr * 64 + mi * 16 + (lane >> 4) * 4 + r;
                int gcol = n0 + wc * 32 + ni * 16 + (lane & 15);
                C[(size_t)grow * 768 + gcol] = f2bf(acc[mi][ni][r]);
            }
}

// Per-layer combined GRU weight from fused P and Whh.
// Wc5[l][np][k]: np = (d>>4)*64 + g*16 + (d&15), k in [0,512)
// k<256 (g-half):  g in {r,z,i_n} -> P_l[k][gate_row];  g==3 (h_n) -> 0
// k>=256 (h-half): g in {r,z,h_n} -> Whh[gate_row][k-256]; g==2 (i_n) -> 0
__global__ void wc5_kernel(const unsigned short* __restrict__ Pall,
                           const float* __restrict__ whh,
                           unsigned short* __restrict__ Wc5) {
    int id = blockIdx.x * 256 + threadIdx.x;          // 5*1024*512 = 2621440
    int l = id >> 19;
    int rem = id & 524287;
    int np = rem >> 9, k = rem & 511;
    int g = (np >> 4) & 3;
    int d = ((np >> 6) << 4) | (np & 15);
    int gate_row = (g == 0) ? d : (g == 1) ? 256 + d : 512 + d;
    unsigned short v;
    if (k < 256) {
        v = (g == 3) ? (unsigned short)0 : Pall[((size_t)(l * 256 + k)) * 768 + gate_row];
    } else {
        v = (g == 2) ? (unsigned short)0 : f2bf(whh[(size_t)gate_row * 256 + (k - 256)]);
    }
    Wc5[id] = v;
}

// ---------------- CSR build (once per launch) ----------------

__global__ void hist_kernel(const int* __restrict__ dst, int* __restrict__ deg) {
    int e = blockIdx.x * 256 + threadIdx.x;
    if (e < NE) atomicAdd(&deg[dst[e]], 1);
}

__global__ __launch_bounds__(1024) void scan_kernel(const int* __restrict__ deg, int* __restrict__ base) {
    __shared__ int part[1024];
    const int t = threadIdx.x;
    const int CH = 20;
    int start = t * CH;
    int s = 0;
    for (int i = 0; i < CH; ++i) { int idx = start + i; if (idx < NN) s += deg[idx]; }
    part[t] = s; __syncthreads();
    for (int off = 1; off < 1024; off <<= 1) {
        int v = (t >= off) ? part[t - off] : 0;
        __syncthreads();
        part[t] += v;
        __syncthreads();
    }
    int run = (t == 0) ? 0 : part[t - 1];
    for (int i = 0; i < CH; ++i) {
        int idx = start + i;
        if (idx < NN) { base[idx] = run; run += deg[idx]; }
    }
    if (t == 1023) base[NN] = run;
}

__global__ void fill_kernel(const int* __restrict__ src, const int* __restrict__ dst,
                            const float* __restrict__ attr, const int* __restrict__ base,
                            int* __restrict__ cursor, int* __restrict__ ssrc,
                            float* __restrict__ sattr) {
    int e = blockIdx.x * 256 + threadIdx.x;
    if (e >= NE) return;
    int d = dst[e];
    int pos = base[d] + atomicAdd(&cursor[d], 1);
    ssrc[pos] = src[e];
    sattr[pos] = attr[e];
}

// ---------------- aggregation: g[n] = sum_{e: dst=n} attr[e]*h_bf[src[e]] ----------------
__global__ __launch_bounds__(256) void gather_agg_kernel(const unsigned short* __restrict__ Hbf,
                                                         const int* __restrict__ base,
                                                         const int* __restrict__ ssrc,
                                                         const float* __restrict__ sattr,
                                                         unsigned short* __restrict__ AggBf) {
    int node = blockIdx.x * 4 + (threadIdx.x >> 6);
    if (node >= NN) return;
    int lane = threadIdx.x & 63;
    int half = lane >> 5;
    int dl = lane & 31;
    int b0 = base[node], b1 = base[node + 1];
    float ac[8] = {0.f, 0.f, 0.f, 0.f, 0.f, 0.f, 0.f, 0.f};
    for (int p = b0 + half; p < b1; p += 2) {
        int s = ssrc[p];
        float a = sattr[p];
        int4v v = *reinterpret_cast<const int4v*>(Hbf + (size_t)s * 256 + dl * 8);
        ac[0] += a * bf2f((unsigned short)(v.x & 0xffff));
        ac[1] += a * bf2f((unsigned short)((unsigned)v.x >> 16));
        ac[2] += a * bf2f((unsigned short)(v.y & 0xffff));
        ac[3] += a * bf2f((unsigned short)((unsigned)v.y >> 16));
        ac[4] += a * bf2f((unsigned short)(v.z & 0xffff));
        ac[5] += a * bf2f((unsigned short)((unsigned)v.z >> 16));
        ac[6] += a * bf2f((unsigned short)(v.w & 0xffff));
        ac[7] += a * bf2f((unsigned short)((unsigned)v.w >> 16));
    }
#pragma unroll
    for (int j = 0; j < 8; ++j) ac[j] += __shfl_xor(ac[j], 32);
    if (half == 0) {
        int4v o;
        o.x = (int)((unsigned)f2bf(ac[0]) | ((unsigned)f2bf(ac[1]) << 16));
        o.y = (int)((unsigned)f2bf(ac[2]) | ((unsigned)f2bf(ac[3]) << 16));
        o.z = (int)((unsigned)f2bf(ac[4]) | ((unsigned)f2bf(ac[5]) << 16));
        o.w = (int)((unsigned)f2bf(ac[6]) | ((unsigned)f2bf(ac[7]) << 16));
        *reinterpret_cast<int4v*>(AggBf + (size_t)node * 256 + dl * 8) = o;
    }
}

// ---------------- fused GRU+transform GEMM: C = [g|h] (M x 512) @ Wc_l^T (1024 x 512) --------
// 8 waves (512 thr) as 4x2, wave tile 32x64 -> acc[2][4]=32 regs (total ~110 <= 128)
// -> 4 waves/SIMD at 32KB single-buffered LDS = 2 blocks x 8 waves = 16 waves/CU.
// m97 2-barrier loop, XCD-chunked swizzle (1264 = 8*158), in-register gate epilogue.
__global__ __launch_bounds__(512) void gru_kernel(const unsigned short* __restrict__ Abf,
                                                  const unsigned short* __restrict__ Hbf,
                                                  const unsigned short* __restrict__ Wc,
                                                  const float* __restrict__ b_ih,
                                                  const float* __restrict__ b_hh,
                                                  const float* __restrict__ h_in,
                                                  float* __restrict__ h_out,
                                                  unsigned short* __restrict__ Hbf_out) {
    __shared__ __align__(16) unsigned short As[128 * 64];
    __shared__ __align__(16) unsigned short Bs[128 * 64];
    const int t = threadIdx.x;
    const int lane = t & 63;
    const int w = t >> 6;                              // 0..7
    const int wr = w >> 1, wc = w & 1;                 // 4 x 2
    int b = blockIdx.x;
    int ww = (b & 7) * 158 + (b >> 3);                 // XCD-chunked (1264 = 8*158, exact)
    const int mt = ww >> 3, nt = ww & 7;
    const int m0 = mt * 128;
    const int n0 = nt * 128;

    f32x4 acc[2][4];
    const f32x4 z4 = {0.f, 0.f, 0.f, 0.f};
#pragma unroll
    for (int i = 0; i < 2; ++i)
#pragma unroll
        for (int j = 0; j < 4; ++j) acc[i][j] = z4;

    for (int kt = 0; kt < 8; ++kt) {
        const unsigned short* aptr = (kt < 4) ? Abf : Hbf;
        const int ka = (kt & 3) * 64;
        const int kb = kt * 64;
#pragma unroll
        for (int i = 0; i < 2; ++i) {                  // 1024 chunks each, 512 threads
            int cb = i * 512 + (w << 6);
            int c = cb + lane;
            int row = c >> 3, sl = c & 7;
            int gsl = sl ^ (row & 7);                  // pre-swizzled global source, linear LDS dest
            gload16(aptr + (size_t)(m0 + row) * 256 + ka + gsl * 8, &As[cb * 8]);
            gload16(Wc + (size_t)(n0 + row) * 512 + kb + gsl * 8, &Bs[cb * 8]);
        }
        __syncthreads();                               // vmcnt(0) drain + barrier (hidden by TLP)
#pragma unroll
        for (int ks = 0; ks < 2; ++ks) {
            const int slot = ks * 4 + (lane >> 4);
            bf16x8 a[2], bfr[4];
#pragma unroll
            for (int mi = 0; mi < 2; ++mi) {
                int row = wr * 32 + mi * 16 + (lane & 15);
                a[mi] = *reinterpret_cast<const bf16x8*>(&As[row * 64 + ((slot ^ (row & 7)) << 3)]);
            }
#pragma unroll
            for (int g = 0; g < 4; ++g) {
                int row = wc * 64 + g * 16 + (lane & 15);
                bfr[g] = *reinterpret_cast<const bf16x8*>(&Bs[row * 64 + ((slot ^ (row & 7)) << 3)]);
            }
#pragma unroll
            for (int mi = 0; mi < 2; ++mi)
#pragma unroll
                for (int g = 0; g < 4; ++g)
                    acc[mi][g] = __builtin_amdgcn_mfma_f32_16x16x32_bf16(a[mi], bfr[g], acc[mi][g], 0, 0, 0);
        }
        __syncthreads();
    }

    // ---- fused GRU gate epilogue (all 4 gates in-register per thread) ----
    const int c = lane & 15;
    const int d = (nt * 2 + wc) * 16 + c;              // output channel 0..255
    const float bir = b_ih[d],       bhr = b_hh[d];
    const float biz = b_ih[256 + d], bhz = b_hh[256 + d];
    const float bin_ = b_ih[512 + d], bhn = b_hh[512 + d];
#pragma unroll
    for (int mi = 0; mi < 2; ++mi)
#pragma unroll
        for (int r = 0; r < 4; ++r) {
            int grow = m0 + wr * 32 + mi * 16 + (lane >> 4) * 4 + r;
            if (grow >= NN) continue;
            float rr = fast_sigmoid(acc[mi][0][r] + bir + bhr);
            float zz = fast_sigmoid(acc[mi][1][r] + biz + bhz);
            float nn = fast_tanh(acc[mi][2][r] + bin_ + rr * (acc[mi][3][r] + bhn));
            float hp = h_in[(size_t)grow * 256 + d];
            float hv = (1.f - zz) * nn + zz * hp;
            h_out[(size_t)grow * 256 + d] = hv;
            Hbf_out[(size_t)grow * 256 + d] = f2bf(hv);
        }
}

// ---------------- launch ----------------

extern "C" void kernel_launch(void* const* d_in, const int* in_sizes, int n_in,
                              void* d_out, int out_size, void* d_ws, size_t ws_size,
                              hipStream_t stream) {
    const float* x     = (const float*)d_in[0];
    const int*   eidx  = (const int*)d_in[1];
    const float* eattr = (const float*)d_in[2];
    const float* W     = (const float*)d_in[3];
    const float* wih   = (const float*)d_in[4];
    const float* whh   = (const float*)d_in[5];
    const float* bih   = (const float*)d_in[6];
    const float* bhh   = (const float*)d_in[7];
    float* out = (float*)d_out;
    const int* esrc = eidx;
    const int* edst = eidx + NE;

    char* p = (char*)d_ws;
    auto alloc = [&](size_t bytes) -> char* {
        char* r = p; p += (bytes + 255) & ~(size_t)255; return r;
    };
    unsigned short* hbfA  = (unsigned short*)alloc((size_t)NN * DD * 2);
    unsigned short* hbfB  = (unsigned short*)alloc((size_t)NN * DD * 2);
    unsigned short* aggbf = (unsigned short*)alloc((size_t)NN * DD * 2);
    unsigned short* wnb   = (unsigned short*)alloc((size_t)5 * DD * DD * 2);   // W natural, bf16
    unsigned short* wihb  = (unsigned short*)alloc((size_t)768 * DD * 2);      // Wih natural, bf16
    unsigned short* pall  = (unsigned short*)alloc((size_t)1280 * 768 * 2);    // P = W @ Wih^T
    unsigned short* wc5   = (unsigned short*)alloc((size_t)5 * 1024 * 512 * 2);
    int*   deg    = (int*)alloc((size_t)NN * 4);
    int*   basep  = (int*)alloc((size_t)(NN + 1) * 4);
    int*   cursor = (int*)alloc((size_t)NN * 4);
    int*   ssrc   = (int*)alloc((size_t)NE * 4);
    float* sattr  = (float*)alloc((size_t)NE * 4);
    alloc(262144);  // guard slack: padded tile rows (20000..20223) read in-workspace garbage

    hipMemsetAsync(deg, 0, (size_t)NN * 4, stream);
    hipMemsetAsync(cursor, 0, (size_t)NN * 4, stream);

    cast_kernel<<<320, 256, 0, stream>>>(W, wnb, 5 * DD * DD);
    cast_kernel<<<192, 256, 0, stream>>>(wih, wihb, 768 * DD);
    cast_kernel<<<5000, 256, 0, stream>>>(x, hbfA, NN * DD);
    pgemm_kernel<<<dim3(12, 10), 256, 0, stream>>>(wnb, wihb, pall);
    wc5_kernel<<<10240, 256, 0, stream>>>(pall, whh, wc5);
    hist_kernel<<<1250, 256, 0, stream>>>(edst, deg);
    scan_kernel<<<1, 1024, 0, stream>>>(deg, basep);
    fill_kernel<<<1250, 256, 0, stream>>>(esrc, edst, eattr, basep, cursor, ssrc, sattr);

    unsigned short* hb_cur = hbfA;
    unsigned short* hb_nxt = hbfB;
    const float* h_in = x;
    for (int l = 0; l < 5; ++l) {
        gather_agg_kernel<<<5000, 256, 0, stream>>>(hb_cur, basep, ssrc, sattr, aggbf);
        gru_kernel<<<1264, 512, 0, stream>>>(aggbf, hb_cur, wc5 + (size_t)l * 1024 * 512,
                                             bih, bhh, h_in, out, hb_nxt);
        h_in = out;
        unsigned short* tmp = hb_cur; hb_cur = hb_nxt; hb_nxt = tmp;
    }
    (void)in_sizes; (void)n_in; (void)out_size; (void)ws_size;
}